// Round 5
// baseline (93.471 us; speedup 1.0000x reference)
//
#include <hip/hip_runtime.h>

#define B_   4
#define LQ_  256
#define LK_  512
#define DIN_ 512
#define H_   256
#define DV_  512

// 2*log2(e): folded into projections so tanh(x) = 1 - 2*rcp(exp2(x')+1), x'=2x*log2e
#define TANH_SCALE 2.885390081777927f

// =====================================================================
// Kernel A: projections, BOTH outputs transposed:
//   qpT[b][h][i] , kpT[b][h][j]  (pre-scaled by TANH_SCALE)
// TR=4 rows/block -> 768 blocks (3/CU). Thread = one h column, 4 chains.
// K-blocks fully beyond valid_len exit immediately.
// =====================================================================
__global__ __launch_bounds__(256) void proj_kernel(
    const float* __restrict__ Q, const float* __restrict__ K,
    const float* __restrict__ Wq, const float* __restrict__ Wk,
    const float* __restrict__ wv, const int* __restrict__ valid_lens,
    float* __restrict__ qpT, float* __restrict__ kpT, float* __restrict__ wsum) {
  __shared__ float xs[4][DIN_];    // 8 KB
  const int blk = blockIdx.x;
  const bool isQ = blk < (B_ * LQ_ / 4);
  const int flat = (isQ ? blk : blk - B_ * LQ_ / 4) * 4;
  const int b    = isQ ? (flat >> 8) : (flat >> 9);
  const int rloc = isQ ? (flat & (LQ_ - 1)) : (flat & (LK_ - 1));
  const int t = threadIdx.x;       // = h column

  if (!isQ && rloc >= valid_lens[b]) return;   // masked K rows: never read later

  const float* __restrict__ X = (isQ ? Q : K) + (size_t)flat * DIN_;
  const float* __restrict__ W = isQ ? Wq : Wk;

  // stage 4 rows of X: 512 float4 / 256 thr = 2 each (coalesced)
#pragma unroll
  for (int u = 0; u < 2; ++u) {
    const int f = t + 256 * u;               // float4 idx 0..511
    const int r = f >> 7, c4 = (f & 127) << 2;
    *(float4*)&xs[r][c4] = *(const float4*)&X[(size_t)r * DIN_ + c4];
  }
  __syncthreads();

  float acc[4] = {0.f, 0.f, 0.f, 0.f};
  for (int d = 0; d < DIN_; d += 8) {
    float w[8];
#pragma unroll
    for (int u = 0; u < 8; ++u) w[u] = W[(size_t)(d + u) * H_ + t];  // 8 loads in flight
#pragma unroll
    for (int r = 0; r < 4; ++r) {
      const float4 xa = *(const float4*)&xs[r][d];
      const float4 xb = *(const float4*)&xs[r][d + 4];
      acc[r] = fmaf(xa.x, w[0], acc[r]); acc[r] = fmaf(xa.y, w[1], acc[r]);
      acc[r] = fmaf(xa.z, w[2], acc[r]); acc[r] = fmaf(xa.w, w[3], acc[r]);
      acc[r] = fmaf(xb.x, w[4], acc[r]); acc[r] = fmaf(xb.y, w[5], acc[r]);
      acc[r] = fmaf(xb.z, w[6], acc[r]); acc[r] = fmaf(xb.w, w[7], acc[r]);
    }
  }

  float4 o = {acc[0] * TANH_SCALE, acc[1] * TANH_SCALE,
              acc[2] * TANH_SCALE, acc[3] * TANH_SCALE};
  if (isQ) *(float4*)&qpT[((size_t)b * H_ + t) * LQ_ + rloc] = o;
  else     *(float4*)&kpT[((size_t)b * H_ + t) * LK_ + rloc] = o;

  if (blk == 0 && t < 64) {
    float s = wv[t] + wv[t + 64] + wv[t + 128] + wv[t + 192];
#pragma unroll
    for (int off = 32; off; off >>= 1) s += __shfl_xor(s, off);
    if (t == 0) *wsum = s;
  }
}

// =====================================================================
// Kernel B: scores[b,i,j] = Wsum - 2*sum_h wv[h]*rcp(1+exp2(qpT+kpT))
// TI=4 rows, lane=j. q via uniform (scalar) float4 reads from qpT.
// h-loop unrolled x8: 8 kv loads in flight per group. Block/wave masking.
// grid = B * (LQ/4) * (LK/256) = 512 blocks x 256 thr.
// =====================================================================
__global__ __launch_bounds__(256) void scores_kernel(
    const float* __restrict__ qpT, const float* __restrict__ kpT,
    const float* __restrict__ wv, const float* __restrict__ wsum,
    const int* __restrict__ valid_lens, float* __restrict__ scores) {
  const int blk = blockIdx.x;
  const int b  = blk >> 7;
  const int r  = blk & 127;
  const int i0 = (r >> 1) * 4;
  const int jh = (r & 1) * 256;
  const int vl = valid_lens[b];
  if (jh >= vl) return;                          // whole block masked
  const int t = threadIdx.x;
  if (jh + ((t >> 6) << 6) >= vl) return;        // wave-uniform skip
  const int j = jh + t;

  const float* __restrict__ kcol = kpT + (size_t)b * H_ * LK_ + j;
  const float* __restrict__ qcol = qpT + (size_t)b * H_ * LQ_ + i0;
  const float Wsum = *wsum;

  float a0 = 0.f, a1 = 0.f, a2 = 0.f, a3 = 0.f;
  for (int h = 0; h < H_; h += 8) {
    float kv[8];
#pragma unroll
    for (int u = 0; u < 8; ++u) kv[u] = kcol[(size_t)(h + u) * LK_];  // 8 in flight
    const float4 wa = *(const float4*)(wv + h);      // uniform
    const float4 wb = *(const float4*)(wv + h + 4);  // uniform
    const float ww[8] = {wa.x, wa.y, wa.z, wa.w, wb.x, wb.y, wb.z, wb.w};
#pragma unroll
    for (int u = 0; u < 8; ++u) {
      const float4 q4 = *(const float4*)(qcol + (size_t)(h + u) * LQ_);  // uniform
      a0 = fmaf(ww[u], __builtin_amdgcn_rcpf(exp2f(q4.x + kv[u]) + 1.f), a0);
      a1 = fmaf(ww[u], __builtin_amdgcn_rcpf(exp2f(q4.y + kv[u]) + 1.f), a1);
      a2 = fmaf(ww[u], __builtin_amdgcn_rcpf(exp2f(q4.z + kv[u]) + 1.f), a2);
      a3 = fmaf(ww[u], __builtin_amdgcn_rcpf(exp2f(q4.w + kv[u]) + 1.f), a3);
    }
  }
  const size_t o = (size_t)(b * LQ_ + i0) * LK_ + j;
  scores[o]           = fmaf(-2.f, a0, Wsum);
  scores[o + LK_]     = fmaf(-2.f, a1, Wsum);
  scores[o + 2 * LK_] = fmaf(-2.f, a2, Wsum);
  scores[o + 3 * LK_] = fmaf(-2.f, a3, Wsum);
}

// =====================================================================
// Kernel C: masked softmax + AV, TI=4 rows/block, 512 thr, AV unroll x8.
// =====================================================================
__global__ __launch_bounds__(512) void softmax_av_kernel(
    const float* __restrict__ scores, const float* __restrict__ V,
    const int* __restrict__ valid_lens, float* __restrict__ out) {
  __shared__ float4 p4s[LK_];
  __shared__ float redm[8][4];
  __shared__ float reds[8][4];

  const int blk = blockIdx.x;
  const int b = blk >> 6;
  const int i0 = (blk & 63) * 4;
  const int vl = valid_lens[b];
  const int t = threadIdx.x;
  const int lane = t & 63, wave = t >> 6;

  const float* __restrict__ srow = scores + (size_t)(b * LQ_ + i0) * LK_;
  const bool valid = t < vl;
  float s[4], m[4];
#pragma unroll
  for (int ii = 0; ii < 4; ++ii) {
    s[ii] = valid ? srow[ii * LK_ + t] : -3.0e38f;
    m[ii] = s[ii];
  }
#pragma unroll
  for (int off = 32; off; off >>= 1)
#pragma unroll
    for (int ii = 0; ii < 4; ++ii) m[ii] = fmaxf(m[ii], __shfl_xor(m[ii], off));
  if (lane == 0)
#pragma unroll
    for (int ii = 0; ii < 4; ++ii) redm[wave][ii] = m[ii];
  __syncthreads();
  float e[4], sum[4];
#pragma unroll
  for (int ii = 0; ii < 4; ++ii) {
    float mx = redm[0][ii];
#pragma unroll
    for (int w = 1; w < 8; ++w) mx = fmaxf(mx, redm[w][ii]);
    e[ii] = valid ? __expf(s[ii] - mx) : 0.f;
    sum[ii] = e[ii];
  }
#pragma unroll
  for (int off = 32; off; off >>= 1)
#pragma unroll
    for (int ii = 0; ii < 4; ++ii) sum[ii] += __shfl_xor(sum[ii], off);
  if (lane == 0)
#pragma unroll
    for (int ii = 0; ii < 4; ++ii) reds[wave][ii] = sum[ii];
  __syncthreads();
  {
    float4 pv;
    float tot[4];
#pragma unroll
    for (int ii = 0; ii < 4; ++ii) {
      tot[ii] = reds[0][ii];
#pragma unroll
      for (int w = 1; w < 8; ++w) tot[ii] += reds[w][ii];
    }
    pv.x = e[0] * __builtin_amdgcn_rcpf(tot[0]);
    pv.y = e[1] * __builtin_amdgcn_rcpf(tot[1]);
    pv.z = e[2] * __builtin_amdgcn_rcpf(tot[2]);
    pv.w = e[3] * __builtin_amdgcn_rcpf(tot[3]);
    p4s[t] = pv;
  }
  __syncthreads();

  const float* __restrict__ Vb = V + (size_t)b * LK_ * DV_ + t;
  float a[4] = {0.f, 0.f, 0.f, 0.f};
  int j = 0;
  const int jv = vl & ~7;
  for (; j < jv; j += 8) {
    float v[8];
#pragma unroll
    for (int u = 0; u < 8; ++u) v[u] = Vb[(size_t)(j + u) * DV_];
#pragma unroll
    for (int u = 0; u < 8; ++u) {
      const float4 pp = p4s[j + u];
      a[0] = fmaf(pp.x, v[u], a[0]); a[1] = fmaf(pp.y, v[u], a[1]);
      a[2] = fmaf(pp.z, v[u], a[2]); a[3] = fmaf(pp.w, v[u], a[3]);
    }
  }
  for (; j < vl; ++j) {
    const float v = Vb[(size_t)j * DV_];
    const float4 pp = p4s[j];
    a[0] = fmaf(pp.x, v, a[0]); a[1] = fmaf(pp.y, v, a[1]);
    a[2] = fmaf(pp.z, v, a[2]); a[3] = fmaf(pp.w, v, a[3]);
  }
#pragma unroll
  for (int ii = 0; ii < 4; ++ii)
    out[(size_t)(b * LQ_ + i0 + ii) * DV_ + t] = a[ii];
}

extern "C" void kernel_launch(void* const* d_in, const int* in_sizes, int n_in,
                              void* d_out, int out_size, void* d_ws, size_t ws_size,
                              hipStream_t stream) {
  const float* queries    = (const float*)d_in[0];
  const float* keys       = (const float*)d_in[1];
  const float* values     = (const float*)d_in[2];
  const int*   valid_lens = (const int*)d_in[3];
  const float* Wq         = (const float*)d_in[4];
  const float* Wk         = (const float*)d_in[5];
  const float* wv         = (const float*)d_in[6];
  float* out = (float*)d_out;

  char* ws = (char*)d_ws;
  float* qpT  = (float*)ws;                          // B*H*LQ  = 1 MB
  float* kpT  = (float*)(ws + (size_t)(1 << 20));    // B*H*LK  = 2 MB
  float* sc   = (float*)(ws + (size_t)(3 << 20));    // B*LQ*LK = 2 MB
  float* wsum = (float*)(ws + (size_t)(5 << 20));    // 4 B

  proj_kernel<<<(B_ * LQ_ + B_ * LK_) / 4, 256, 0, stream>>>(
      queries, keys, Wq, Wk, wv, valid_lens, qpT, kpT, wsum);
  scores_kernel<<<B_ * (LQ_ / 4) * (LK_ / 256), 256, 0, stream>>>(
      qpT, kpT, wv, wsum, valid_lens, sc);
  softmax_av_kernel<<<B_ * (LQ_ / 4), 512, 0, stream>>>(
      sc, values, valid_lens, out);
}